// Round 1
// baseline (752.820 us; speedup 1.0000x reference)
//
#include <hip/hip_runtime.h>

#define FFT_N 1024
#define NT    256

__device__ __forceinline__ float2 cmul(float2 a, float2 b) {
    return make_float2(a.x * b.x - a.y * b.y, a.x * b.y + a.y * b.x);
}

// Radix-4 Stockham FFT, N=1024, 256 threads, one butterfly per thread per stage.
// Input in A, output ends in Bf (5 stages, odd). Barrier after every stage.
__device__ __forceinline__ void fft1024(float2* A, float2* Bf, const float2* tw, int tid) {
    float2* src = A;
    float2* dst = Bf;
    for (int Ns = 1; Ns < FFT_N; Ns *= 4) {
        float2 v0 = src[tid];
        float2 v1 = src[tid + 256];
        float2 v2 = src[tid + 512];
        float2 v3 = src[tid + 768];
        int jm = tid & (Ns - 1);
        if (Ns > 1) {
            int tb = jm * (FFT_N / (4 * Ns));
            v1 = cmul(v1, tw[tb]);
            v2 = cmul(v2, tw[2 * tb]);
            v3 = cmul(v3, tw[3 * tb]);
        }
        // radix-4 DFT (forward, e^{-j})
        float2 a = make_float2(v0.x + v2.x, v0.y + v2.y);
        float2 b = make_float2(v0.x - v2.x, v0.y - v2.y);
        float2 c = make_float2(v1.x + v3.x, v1.y + v3.y);
        float2 d = make_float2(v1.x - v3.x, v1.y - v3.y);
        int idxD = (tid & ~(Ns - 1)) * 4 + jm;  // (tid/Ns)*(4*Ns) + jm
        dst[idxD]          = make_float2(a.x + c.x, a.y + c.y);
        dst[idxD + Ns]     = make_float2(b.x + d.y, b.y - d.x);  // b - j*d
        dst[idxD + 2 * Ns] = make_float2(a.x - c.x, a.y - c.y);
        dst[idxD + 3 * Ns] = make_float2(b.x - d.y, b.y + d.x);  // b + j*d
        __syncthreads();
        float2* tmp = src; src = dst; dst = tmp;
    }
}

// Accumulate partial sum of Re( conj(H_f) * T_f * conj(R_f) ) over this thread's
// 4 frequencies. X = FFT(h + j t) in bufB, Z = FFT(r_row0 + j r_row1) in bufZ.
// mode 0: R = (Z + conj(Z_-f))/2   (row0's r)
// mode 1: R = (Z - conj(Z_-f))/(2j) (row1's r)
__device__ __forceinline__ float accum_score(const float2* X, const float2* Z, int tid, int mode) {
    float acc = 0.0f;
#pragma unroll
    for (int kk = 0; kk < 4; ++kk) {
        int f = tid + kk * 256;
        int g = (FFT_N - f) & (FFT_N - 1);
        float2 P = X[f];
        float2 Q = X[g];  // X_{-f}
        // H = (P + conj(Q))/2 ; T = (P - conj(Q))/(2j)
        float2 Hf = make_float2(0.5f * (P.x + Q.x), 0.5f * (P.y - Q.y));
        float2 Tf = make_float2(0.5f * (P.y + Q.y), -0.5f * (P.x - Q.x));
        // U = conj(H) * T
        float2 U = make_float2(Hf.x * Tf.x + Hf.y * Tf.y, Hf.x * Tf.y - Hf.y * Tf.x);
        float2 Zf = Z[f];
        float2 Zg = Z[g];
        float2 Rf;
        if (mode == 0)
            Rf = make_float2(0.5f * (Zf.x + Zg.x), 0.5f * (Zf.y - Zg.y));
        else
            Rf = make_float2(0.5f * (Zf.y + Zg.y), -0.5f * (Zf.x - Zg.x));
        // Re(U * conj(Rf))
        acc += U.x * Rf.x + U.y * Rf.y;
    }
    return acc;
}

__global__ __launch_bounds__(NT) void hole_fft_kernel(
    const float* __restrict__ h, const float* __restrict__ r, const float* __restrict__ t,
    float* __restrict__ out, int B)
{
    __shared__ float2 bufA[FFT_N];
    __shared__ float2 bufB[FFT_N];
    __shared__ float2 bufZ[FFT_N];
    __shared__ float2 tw[FFT_N];
    __shared__ float red0[4];
    __shared__ float red1[4];

    const int tid = threadIdx.x;
    const int row0 = blockIdx.x * 2;
    const int row1 = row0 + 1;

    const float* hp0 = h + (size_t)row0 * FFT_N;
    const float* hp1 = h + (size_t)row1 * FFT_N;
    const float* rp0 = r + (size_t)row0 * FFT_N;
    const float* rp1 = r + (size_t)row1 * FFT_N;
    const float* tp0 = t + (size_t)row0 * FFT_N;
    const float* tp1 = t + (size_t)row1 * FFT_N;

    // Twiddle table tw[k] = e^{-2*pi*i*k/N}, and load Z = r0 + j r1
#pragma unroll
    for (int kk = 0; kk < 4; ++kk) {
        int k = tid + kk * 256;
        float ang = -6.283185307179586f * (float)k * (1.0f / (float)FFT_N);
        float s, c;
        __sincosf(ang, &s, &c);
        tw[k] = make_float2(c, s);
        bufA[k] = make_float2(rp0[k], rp1[k]);
    }
    __syncthreads();

    // Z = FFT(r0 + j r1) -> bufB
    fft1024(bufA, bufB, tw, tid);

    // stash Z, load X0 input
#pragma unroll
    for (int kk = 0; kk < 4; ++kk) {
        int k = tid + kk * 256;
        bufZ[k] = bufB[k];
        bufA[k] = make_float2(hp0[k], tp0[k]);
    }
    __syncthreads();

    // X0 = FFT(h0 + j t0) -> bufB
    fft1024(bufA, bufB, tw, tid);

    float acc0 = accum_score(bufB, bufZ, tid, 0);

    // load X1 input (bufA not referenced by accum); barrier before FFT overwrites bufB
#pragma unroll
    for (int kk = 0; kk < 4; ++kk) {
        int k = tid + kk * 256;
        bufA[k] = make_float2(hp1[k], tp1[k]);
    }
    __syncthreads();

    // X1 = FFT(h1 + j t1) -> bufB
    fft1024(bufA, bufB, tw, tid);

    float acc1 = accum_score(bufB, bufZ, tid, 1);

    // reduce acc0/acc1 across 256 threads: wave butterfly, then LDS across 4 waves
#pragma unroll
    for (int off = 32; off > 0; off >>= 1) {
        acc0 += __shfl_down(acc0, off);
        acc1 += __shfl_down(acc1, off);
    }
    const int lane = tid & 63;
    const int wv = tid >> 6;
    if (lane == 0) {
        red0[wv] = acc0;
        red1[wv] = acc1;
    }
    __syncthreads();
    if (tid == 0) {
        float s0 = red0[0] + red0[1] + red0[2] + red0[3];
        float s1 = red1[0] + red1[1] + red1[2] + red1[3];
        out[row0] = s0 * (1.0f / (float)FFT_N);
        out[row1] = s1 * (1.0f / (float)FFT_N);
    }
}

extern "C" void kernel_launch(void* const* d_in, const int* in_sizes, int n_in,
                              void* d_out, int out_size, void* d_ws, size_t ws_size,
                              hipStream_t stream) {
    const float* h = (const float*)d_in[0];
    const float* r = (const float*)d_in[1];
    const float* t = (const float*)d_in[2];
    float* out = (float*)d_out;
    int B = out_size;  // 131072 rows
    int nblocks = B / 2;
    hipLaunchKernelGGL(hole_fft_kernel, dim3(nblocks), dim3(NT), 0, stream,
                       h, r, t, out, B);
}

// Round 2
// 520.140 us; speedup vs baseline: 1.4473x; 1.4473x over previous
//
#include <hip/hip_runtime.h>

#define FFT_N 1024
#define NT    256

// LDS bank swizzle for float2 (8B) elements: bank-pair = index mod 16.
// Folds bits [7:4] and [9:8] of the index into the low 4 bits.
// Verified per quarter-wave (16 lanes): all Stockham stage reads/writes are
// conflict-free with this swizzle + the Ns=4 thread->butterfly permutation.
__device__ __forceinline__ int swz(int a) {
    return a ^ ((a >> 4) & 15) ^ (((a >> 8) & 3) << 2);
}

__device__ __forceinline__ float2 cmul(float2 a, float2 b) {
    return make_float2(a.x * b.x - a.y * b.y, a.x * b.y + a.y * b.x);
}

// Radix-4 Stockham FFT, N=1024, 256 threads, one butterfly/thread/stage.
// Twiddles computed on the fly (sincos + complex powers). Result ends in Bf.
__device__ __forceinline__ void fft1024(float2* A, float2* Bf, int tid) {
    float2* src = A;
    float2* dst = Bf;
#pragma unroll
    for (int Ns = 1; Ns < FFT_N; Ns *= 4) {
        // At Ns=4 reassign butterflies so strided writes de-alias under swz().
        const int b = (Ns == 4) ? (((tid & 3) << 6) | (tid >> 2)) : tid;
        float2 v0 = src[swz(b)];
        float2 v1 = src[swz(b + 256)];
        float2 v2 = src[swz(b + 512)];
        float2 v3 = src[swz(b + 768)];
        const int jm = b & (Ns - 1);
        if (Ns > 1) {
            float ang = (-6.283185307179586f / (float)(4 * Ns)) * (float)jm;
            float sn, cs;
            __sincosf(ang, &sn, &cs);
            float2 w1 = make_float2(cs, sn);
            float2 w2 = cmul(w1, w1);
            float2 w3 = cmul(w2, w1);
            v1 = cmul(v1, w1);
            v2 = cmul(v2, w2);
            v3 = cmul(v3, w3);
        }
        // radix-4 DFT (forward, e^{-j})
        float2 a  = make_float2(v0.x + v2.x, v0.y + v2.y);
        float2 bb = make_float2(v0.x - v2.x, v0.y - v2.y);
        float2 c  = make_float2(v1.x + v3.x, v1.y + v3.y);
        float2 d  = make_float2(v1.x - v3.x, v1.y - v3.y);
        const int idxD = ((b & ~(Ns - 1)) << 2) + jm;
        dst[swz(idxD)]           = make_float2(a.x + c.x, a.y + c.y);
        dst[swz(idxD + Ns)]      = make_float2(bb.x + d.y, bb.y - d.x);  // b - j*d
        dst[swz(idxD + 2 * Ns)]  = make_float2(a.x - c.x, a.y - c.y);
        dst[swz(idxD + 3 * Ns)]  = make_float2(bb.x - d.y, bb.y + d.x); // b + j*d
        __syncthreads();
        float2* tmp = src; src = dst; dst = tmp;
    }
}

// Partial sum of Re( conj(H_f) * T_f * conj(R_f) ) over this thread's 4 freqs.
// X = FFT(h + j t), Z = FFT(r_row0 + j r_row1).
// mode 0: R = (Z + conj(Z_-f))/2 ; mode 1: R = (Z - conj(Z_-f))/(2j)
__device__ __forceinline__ float accum_score(const float2* X, const float2* Z, int tid, int mode) {
    float acc = 0.0f;
#pragma unroll
    for (int kk = 0; kk < 4; ++kk) {
        int f = tid + kk * 256;
        int g = (FFT_N - f) & (FFT_N - 1);
        float2 P = X[swz(f)];
        float2 Q = X[swz(g)];  // X_{-f}
        float2 Hf = make_float2(0.5f * (P.x + Q.x), 0.5f * (P.y - Q.y));
        float2 Tf = make_float2(0.5f * (P.y + Q.y), -0.5f * (P.x - Q.x));
        // U = conj(H) * T
        float2 U = make_float2(Hf.x * Tf.x + Hf.y * Tf.y, Hf.x * Tf.y - Hf.y * Tf.x);
        float2 Zf = Z[swz(f)];
        float2 Zg = Z[swz(g)];
        float2 Rf;
        if (mode == 0)
            Rf = make_float2(0.5f * (Zf.x + Zg.x), 0.5f * (Zf.y - Zg.y));
        else
            Rf = make_float2(0.5f * (Zf.y + Zg.y), -0.5f * (Zf.x - Zg.x));
        acc += U.x * Rf.x + U.y * Rf.y;  // Re(U * conj(Rf))
    }
    return acc;
}

__global__ __launch_bounds__(NT) void hole_fft_kernel(
    const float* __restrict__ h, const float* __restrict__ r, const float* __restrict__ t,
    float* __restrict__ out, int B)
{
    __shared__ float2 bufA[FFT_N];
    __shared__ float2 bufB[FFT_N];
    __shared__ float2 bufZ[FFT_N];
    __shared__ float red0[4];
    __shared__ float red1[4];

    const int tid = threadIdx.x;
    const int row0 = blockIdx.x * 2;
    const int row1 = row0 + 1;

    const float4* h4_0 = (const float4*)(h + (size_t)row0 * FFT_N);
    const float4* h4_1 = (const float4*)(h + (size_t)row1 * FFT_N);
    const float4* r4_0 = (const float4*)(r + (size_t)row0 * FFT_N);
    const float4* r4_1 = (const float4*)(r + (size_t)row1 * FFT_N);
    const float4* t4_0 = (const float4*)(t + (size_t)row0 * FFT_N);
    const float4* t4_1 = (const float4*)(t + (size_t)row1 * FFT_N);

    // Preload all six float4 streams (latency hides under the FFTs).
    float4 rv0 = r4_0[tid];
    float4 rv1 = r4_1[tid];
    float4 hv0 = h4_0[tid];
    float4 tv0 = t4_0[tid];
    float4 hv1 = h4_1[tid];
    float4 tv1 = t4_1[tid];

    const int a0 = 4 * tid;
    // Z input: r0 + j r1
    bufA[swz(a0 + 0)] = make_float2(rv0.x, rv1.x);
    bufA[swz(a0 + 1)] = make_float2(rv0.y, rv1.y);
    bufA[swz(a0 + 2)] = make_float2(rv0.z, rv1.z);
    bufA[swz(a0 + 3)] = make_float2(rv0.w, rv1.w);
    __syncthreads();

    // Z = FFT(r0 + j r1) -> bufB
    fft1024(bufA, bufB, tid);

    // stash Z, load X0 input (h0 + j t0)
#pragma unroll
    for (int kk = 0; kk < 4; ++kk) {
        int k = tid + kk * 256;
        bufZ[k] = bufB[k];  // raw copy: same permutation both sides
    }
    bufA[swz(a0 + 0)] = make_float2(hv0.x, tv0.x);
    bufA[swz(a0 + 1)] = make_float2(hv0.y, tv0.y);
    bufA[swz(a0 + 2)] = make_float2(hv0.z, tv0.z);
    bufA[swz(a0 + 3)] = make_float2(hv0.w, tv0.w);
    __syncthreads();

    // X0 = FFT(h0 + j t0) -> bufB
    fft1024(bufA, bufB, tid);

    float acc0 = accum_score(bufB, bufZ, tid, 0);

    // load X1 input; barrier below (end of fill) orders accum reads vs overwrite
    bufA[swz(a0 + 0)] = make_float2(hv1.x, tv1.x);
    bufA[swz(a0 + 1)] = make_float2(hv1.y, tv1.y);
    bufA[swz(a0 + 2)] = make_float2(hv1.z, tv1.z);
    bufA[swz(a0 + 3)] = make_float2(hv1.w, tv1.w);
    __syncthreads();

    // X1 = FFT(h1 + j t1) -> bufB
    fft1024(bufA, bufB, tid);

    float acc1 = accum_score(bufB, bufZ, tid, 1);

    // reduce across 256 threads
#pragma unroll
    for (int off = 32; off > 0; off >>= 1) {
        acc0 += __shfl_down(acc0, off);
        acc1 += __shfl_down(acc1, off);
    }
    const int lane = tid & 63;
    const int wv = tid >> 6;
    if (lane == 0) {
        red0[wv] = acc0;
        red1[wv] = acc1;
    }
    __syncthreads();
    if (tid == 0) {
        float s0 = red0[0] + red0[1] + red0[2] + red0[3];
        float s1 = red1[0] + red1[1] + red1[2] + red1[3];
        out[row0] = s0 * (1.0f / (float)FFT_N);
        out[row1] = s1 * (1.0f / (float)FFT_N);
    }
}

extern "C" void kernel_launch(void* const* d_in, const int* in_sizes, int n_in,
                              void* d_out, int out_size, void* d_ws, size_t ws_size,
                              hipStream_t stream) {
    const float* h = (const float*)d_in[0];
    const float* r = (const float*)d_in[1];
    const float* t = (const float*)d_in[2];
    float* out = (float*)d_out;
    int B = out_size;  // 131072 rows
    int nblocks = B / 2;
    hipLaunchKernelGGL(hole_fft_kernel, dim3(nblocks), dim3(NT), 0, stream,
                       h, r, t, out, B);
}

// Round 3
// 438.475 us; speedup vs baseline: 1.7169x; 1.1862x over previous
//
#include <hip/hip_runtime.h>

#define FFT_N 1024
#define NT    256

// LDS bank swizzle (float2-granular index): GF(2)-linear, so
// swz(a + c) = swz(a) ^ swz(c) whenever a & c == 0. All stage offsets below
// exploit this: one per-thread base + compile-time XOR constants.
__device__ __forceinline__ int swz(int a) {
    return a ^ ((a >> 4) & 15) ^ (((a >> 8) & 3) << 2);
}

__device__ __forceinline__ float2 cmul(float2 a, float2 b) {
    return make_float2(a.x * b.x - a.y * b.y, a.x * b.y + a.y * b.x);
}
__device__ __forceinline__ float2 csqr(float2 a) {
    return make_float2(a.x * a.x - a.y * a.y, 2.0f * a.x * a.y);
}

__device__ __forceinline__ float2& lds2(float2* p, int byteoff) {
    return *(float2*)((char*)p + byteoff);
}

// Forward radix-4 DFT core: X_k = sum v_n (-j)^{nk}
__device__ __forceinline__ void dft4(float2 v0, float2 v1, float2 v2, float2 v3,
                                     float2& o0, float2& o1, float2& o2, float2& o3) {
    float2 a = make_float2(v0.x + v2.x, v0.y + v2.y);
    float2 b = make_float2(v0.x - v2.x, v0.y - v2.y);
    float2 c = make_float2(v1.x + v3.x, v1.y + v3.y);
    float2 d = make_float2(v1.x - v3.x, v1.y - v3.y);
    o0 = make_float2(a.x + c.x, a.y + c.y);
    o1 = make_float2(b.x + d.y, b.y - d.x);   // b - j*d
    o2 = make_float2(a.x - c.x, a.y - c.y);
    o3 = make_float2(b.x - d.y, b.y + d.x);   // b + j*d
}

struct Pre {
    int rb;                      // swz(tid)<<3 : read base (Ns=16/64/256) and f-reads; also wb256
    int pb;                      // swz(perm(tid))<<3 : Ns=4 read base
    int s1w;                     // swz(4*tid)<<3 : fused stage-1 write base
    int wb4, wb16, wb64;         // per-stage write bases (byte)
    float2 w1[4], w2[4], w3[4];  // twiddles for stages Ns=4,16,64,256
};

// One LDS Stockham stage. Read consts are fixed (256k elements); write consts per stage.
__device__ __forceinline__ void stage(float2* src, float2* dst, int rbase, int wbase,
                                      int c1, int c2, int c3,
                                      float2 w1, float2 w2, float2 w3) {
    float2 v0 = lds2(src, rbase);
    float2 v1 = lds2(src, rbase ^ 2080);
    float2 v2 = lds2(src, rbase ^ 4160);
    float2 v3 = lds2(src, rbase ^ 6240);
    v1 = cmul(v1, w1);
    v2 = cmul(v2, w2);
    v3 = cmul(v3, w3);
    float2 o0, o1, o2, o3;
    dft4(v0, v1, v2, v3, o0, o1, o2, o3);
    lds2(dst, wbase)      = o0;
    lds2(dst, wbase ^ c1) = o1;
    lds2(dst, wbase ^ c2) = o2;
    lds2(dst, wbase ^ c3) = o3;
    __syncthreads();
}

// Full 1024-pt FFT: stage-1 in registers (inputs are elements b+256k), then 4 LDS
// stages ping-ponging P->Q->P->Q->P. Result lands in P.
__device__ __forceinline__ void fft_fused(float2* P, float2* Q,
                                          float2 i0, float2 i1, float2 i2, float2 i3,
                                          const Pre& pr) {
    float2 o0, o1, o2, o3;
    dft4(i0, i1, i2, i3, o0, o1, o2, o3);
    lds2(P, pr.s1w)      = o0;
    lds2(P, pr.s1w ^ 8)  = o1;
    lds2(P, pr.s1w ^ 16) = o2;
    lds2(P, pr.s1w ^ 24) = o3;
    __syncthreads();
    stage(P, Q, pr.pb, pr.wb4,   32,   64,   96, pr.w1[0], pr.w2[0], pr.w3[0]); // Ns=4
    stage(Q, P, pr.rb, pr.wb16, 136,  272,  408, pr.w1[1], pr.w2[1], pr.w3[1]); // Ns=16
    stage(P, Q, pr.rb, pr.wb64, 544, 1088, 1632, pr.w1[2], pr.w2[2], pr.w3[2]); // Ns=64
    stage(Q, P, pr.rb, pr.rb,  2080, 4160, 6240, pr.w1[3], pr.w2[3], pr.w3[3]); // Ns=256 (wb==rb)
}

__global__ __launch_bounds__(NT) void hole_fft_kernel(
    const float* __restrict__ h, const float* __restrict__ r, const float* __restrict__ t,
    float* __restrict__ out, int B)
{
    __shared__ float2 bufA[FFT_N];
    __shared__ float2 bufB[FFT_N];
    __shared__ float red0[4];
    __shared__ float red1[4];

    const int tid = threadIdx.x;
    const int row0 = blockIdx.x * 2;
    const int row1 = row0 + 1;

    // ---- precompute per-thread addressing + twiddles (reused by all 3 FFTs) ----
    Pre pr;
    const int bp = ((tid & 3) << 6) | (tid >> 2);  // Ns=4 butterfly permutation
    pr.rb   = swz(tid) << 3;
    pr.pb   = swz(bp) << 3;
    pr.s1w  = swz(4 * tid) << 3;
    pr.wb4  = swz(((bp  & ~3)   << 2) | (bp  & 3))   << 3;
    pr.wb16 = swz(((tid & ~15)  << 2) | (tid & 15))  << 3;
    pr.wb64 = swz(((tid & ~63)  << 2) | (tid & 63))  << 3;

    {
        const int jms[4]   = { bp & 3, tid & 15, tid & 63, tid & 255 };
        const float inv[4] = { -1.0f / 16.0f, -1.0f / 64.0f, -1.0f / 256.0f, -1.0f / 1024.0f };
#pragma unroll
        for (int s = 0; s < 4; ++s) {
            float rev = (float)jms[s] * inv[s];       // in (-0.25, 0]: pre-reduced
            float2 w = make_float2(__builtin_amdgcn_cosf(rev), __builtin_amdgcn_sinf(rev));
            pr.w1[s] = w;
            pr.w2[s] = csqr(w);
            pr.w3[s] = cmul(pr.w2[s], w);
        }
    }

    // g-side (negated-frequency) read addresses for the Parseval accumulation
    int ga[4];
#pragma unroll
    for (int k = 0; k < 4; ++k) {
        int f = tid + 256 * k;
        int g = (FFT_N - f) & (FFT_N - 1);
        ga[k] = swz(g) << 3;
    }

    // ---- strided global loads (coalesced per instruction); element f = tid + 256k ----
    const float* r0p = r + (size_t)row0 * FFT_N;
    const float* r1p = r + (size_t)row1 * FFT_N;
    const float* h0p = h + (size_t)row0 * FFT_N;
    const float* h1p = h + (size_t)row1 * FFT_N;
    const float* t0p = t + (size_t)row0 * FFT_N;
    const float* t1p = t + (size_t)row1 * FFT_N;

    float2 z0 = make_float2(r0p[tid],       r1p[tid]);
    float2 z1 = make_float2(r0p[tid + 256], r1p[tid + 256]);
    float2 z2 = make_float2(r0p[tid + 512], r1p[tid + 512]);
    float2 z3 = make_float2(r0p[tid + 768], r1p[tid + 768]);
    float2 x00 = make_float2(h0p[tid],       t0p[tid]);
    float2 x01 = make_float2(h0p[tid + 256], t0p[tid + 256]);
    float2 x02 = make_float2(h0p[tid + 512], t0p[tid + 512]);
    float2 x03 = make_float2(h0p[tid + 768], t0p[tid + 768]);
    float2 x10 = make_float2(h1p[tid],       t1p[tid]);
    float2 x11 = make_float2(h1p[tid + 256], t1p[tid + 256]);
    float2 x12 = make_float2(h1p[tid + 512], t1p[tid + 512]);
    float2 x13 = make_float2(h1p[tid + 768], t1p[tid + 768]);

    // ---- Z = FFT(r0 + j r1): (A,B), result in A; extract to registers ----
    fft_fused(bufA, bufB, z0, z1, z2, z3, pr);

    float2 Zf[4], Zg[4];
#pragma unroll
    for (int k = 0; k < 4; ++k) {
        int fc = (k == 0) ? 0 : (k == 1) ? 2080 : (k == 2) ? 4160 : 6240;
        Zf[k] = lds2(bufA, pr.rb ^ fc);
        Zg[k] = lds2(bufA, ga[k]);
    }
    // (no barrier needed: X0's first LDS write targets bufB; bufA is only written
    //  after X0's stage-1 barrier, which orders it after all Z reads above)

    // ---- X0 = FFT(h0 + j t0): (B,A), result in B ----
    fft_fused(bufB, bufA, x00, x01, x02, x03, pr);

    float acc0 = 0.0f;
#pragma unroll
    for (int k = 0; k < 4; ++k) {
        int fc = (k == 0) ? 0 : (k == 1) ? 2080 : (k == 2) ? 4160 : 6240;
        float2 P = lds2(bufB, pr.rb ^ fc);
        float2 Q = lds2(bufB, ga[k]);
        float2 Hf = make_float2(0.5f * (P.x + Q.x), 0.5f * (P.y - Q.y));
        float2 Tf = make_float2(0.5f * (P.y + Q.y), -0.5f * (P.x - Q.x));
        float2 U  = make_float2(Hf.x * Tf.x + Hf.y * Tf.y, Hf.x * Tf.y - Hf.y * Tf.x);
        float2 Rf = make_float2(0.5f * (Zf[k].x + Zg[k].x), 0.5f * (Zf[k].y - Zg[k].y));
        acc0 += U.x * Rf.x + U.y * Rf.y;
    }

    // ---- X1 = FFT(h1 + j t1): (A,B), result in A ----
    fft_fused(bufA, bufB, x10, x11, x12, x13, pr);

    float acc1 = 0.0f;
#pragma unroll
    for (int k = 0; k < 4; ++k) {
        int fc = (k == 0) ? 0 : (k == 1) ? 2080 : (k == 2) ? 4160 : 6240;
        float2 P = lds2(bufA, pr.rb ^ fc);
        float2 Q = lds2(bufA, ga[k]);
        float2 Hf = make_float2(0.5f * (P.x + Q.x), 0.5f * (P.y - Q.y));
        float2 Tf = make_float2(0.5f * (P.y + Q.y), -0.5f * (P.x - Q.x));
        float2 U  = make_float2(Hf.x * Tf.x + Hf.y * Tf.y, Hf.x * Tf.y - Hf.y * Tf.x);
        float2 Rf = make_float2(0.5f * (Zf[k].y + Zg[k].y), -0.5f * (Zf[k].x - Zg[k].x));
        acc1 += U.x * Rf.x + U.y * Rf.y;
    }

    // ---- reduce across 256 threads ----
#pragma unroll
    for (int off = 32; off > 0; off >>= 1) {
        acc0 += __shfl_down(acc0, off);
        acc1 += __shfl_down(acc1, off);
    }
    const int lane = tid & 63;
    const int wv = tid >> 6;
    if (lane == 0) {
        red0[wv] = acc0;
        red1[wv] = acc1;
    }
    __syncthreads();
    if (tid == 0) {
        float s0 = red0[0] + red0[1] + red0[2] + red0[3];
        float s1 = red1[0] + red1[1] + red1[2] + red1[3];
        out[row0] = s0 * (1.0f / (float)FFT_N);
        out[row1] = s1 * (1.0f / (float)FFT_N);
    }
}

extern "C" void kernel_launch(void* const* d_in, const int* in_sizes, int n_in,
                              void* d_out, int out_size, void* d_ws, size_t ws_size,
                              hipStream_t stream) {
    const float* h = (const float*)d_in[0];
    const float* r = (const float*)d_in[1];
    const float* t = (const float*)d_in[2];
    float* out = (float*)d_out;
    int B = out_size;  // 131072 rows
    int nblocks = B / 2;
    hipLaunchKernelGGL(hole_fft_kernel, dim3(nblocks), dim3(NT), 0, stream,
                       h, r, t, out, B);
}